// Round 1
// baseline (755.962 us; speedup 1.0000x reference)
//
#include <hip/hip_runtime.h>

#define NEG_SLOPE 0.2f
#define LN_EPS 1e-5f

__device__ __forceinline__ float wsum64(float v){
  #pragma unroll
  for (int o = 32; o >= 1; o >>= 1) v += __shfl_xor(v, o);
  return v;
}
__device__ __forceinline__ float gsum32(float v){
  #pragma unroll
  for (int o = 16; o >= 1; o >>= 1) v += __shfl_xor(v, o);
  return v;
}

// ---------------- CSR build ----------------
__global__ void k_count(const int* __restrict__ dst, int* __restrict__ deg, int E){
  int e = blockIdx.x * blockDim.x + threadIdx.x;
  if (e < E) atomicAdd(&deg[dst[e]], 1);
}

__global__ void k_scan(const int* __restrict__ deg, int* __restrict__ ptr, int n){
  __shared__ int buf[1024];
  int t = threadIdx.x;
  int carry = 0;
  for (int base = 0; base < n; base += 1024){
    int i = base + t;
    int v = (i < n) ? deg[i] : 0;
    __syncthreads();
    buf[t] = v;
    __syncthreads();
    for (int off = 1; off < 1024; off <<= 1){
      int x = (t >= off) ? buf[t - off] : 0;
      __syncthreads();
      buf[t] += x;
      __syncthreads();
    }
    if (i < n) ptr[i] = carry + buf[t] - v;  // exclusive
    carry += buf[1023];
  }
  if (t == 0) ptr[n] = carry;
}

__global__ void k_fill(const int* __restrict__ dst, int* __restrict__ cnt,
                       const int* __restrict__ ptr, int* __restrict__ eid, int E){
  int e = blockIdx.x * blockDim.x + threadIdx.x;
  if (e < E){
    int d = dst[e];
    int pos = atomicAdd(&cnt[d], 1);
    eid[ptr[d] + pos] = e;
  }
}

// loop_attr[n] = sum of incoming edge_attr / max(deg,1) ; 16 lanes per node
__global__ void k_loop_attr(const float* __restrict__ eattr, const int* __restrict__ ptr,
                            const int* __restrict__ eid, float* __restrict__ lattr, int N){
  int idx = blockIdx.x * blockDim.x + threadIdx.x;
  int node = idx >> 4, dim = idx & 15;
  if (node >= N) return;
  int beg = ptr[node], end = ptr[node + 1];
  float s = 0.f;
  for (int i = beg; i < end; i++){
    int e = eid[i];
    s += eattr[(size_t)e * 16 + dim];
  }
  float dg = (float)(end - beg);
  lattr[idx] = s / fmaxf(dg, 1.0f);
}

// ---------------- Y[M,128] = X[M,128] @ W[128,128] + b ----------------
__launch_bounds__(256)
__global__ void k_gemm128(const float* __restrict__ X, const float* __restrict__ W,
                          const float* __restrict__ bias, float* __restrict__ Y, int M){
  __shared__ float Xs[64][129];
  int t = threadIdx.x;
  int rowBase = blockIdx.x * 64;
  int lr = t >> 5, lc = (t & 31) * 4;
  #pragma unroll
  for (int p = 0; p < 8; p++){
    int r = p * 8 + lr, gr = rowBase + r;
    float4 v = make_float4(0.f, 0.f, 0.f, 0.f);
    if (gr < M) v = *(const float4*)(X + (size_t)gr * 128 + lc);
    Xs[r][lc] = v.x; Xs[r][lc + 1] = v.y; Xs[r][lc + 2] = v.z; Xs[r][lc + 3] = v.w;
  }
  __syncthreads();
  int c0 = (t & 31) * 4, r0 = (t >> 5) * 8;
  float4 bv = *(const float4*)(bias + c0);
  float acc[8][4];
  #pragma unroll
  for (int i = 0; i < 8; i++){ acc[i][0] = bv.x; acc[i][1] = bv.y; acc[i][2] = bv.z; acc[i][3] = bv.w; }
  for (int k = 0; k < 128; k++){
    float4 wv = *(const float4*)(W + k * 128 + c0);
    #pragma unroll
    for (int i = 0; i < 8; i++){
      float x = Xs[r0 + i][k];
      acc[i][0] = fmaf(x, wv.x, acc[i][0]);
      acc[i][1] = fmaf(x, wv.y, acc[i][1]);
      acc[i][2] = fmaf(x, wv.z, acc[i][2]);
      acc[i][3] = fmaf(x, wv.w, acc[i][3]);
    }
  }
  #pragma unroll
  for (int i = 0; i < 8; i++){
    int gr = rowBase + r0 + i;
    if (gr < M){
      float4 o; o.x = acc[i][0]; o.y = acc[i][1]; o.z = acc[i][2]; o.w = acc[i][3];
      *(float4*)(Y + (size_t)gr * 128 + c0) = o;
    }
  }
}

// ---------------- GAT layer: one wave per node, online softmax over CSR ----------------
__launch_bounds__(64)
__global__ void k_gat(const float* __restrict__ xl, const float* __restrict__ xr,
                      const float* __restrict__ eattr, const float* __restrict__ lattr,
                      const int* __restrict__ srcs, const int* __restrict__ ptr,
                      const int* __restrict__ eid,
                      const float* __restrict__ We, const float* __restrict__ att,
                      const float* __restrict__ cb, float* __restrict__ hout, int N){
  int t = threadIdx.x;  // lane owns channels t and t+64
  float we0[16], we1[16];
  #pragma unroll
  for (int k = 0; k < 16; k++){ we0[k] = We[k * 128 + t]; we1[k] = We[k * 128 + 64 + t]; }
  float att0 = att[t], att1 = att[64 + t];
  float cb0 = cb[t],  cb1 = cb[64 + t];
  for (int j = 0; j < 4; j++){
    int node = blockIdx.x * 4 + j;
    if (node >= N) break;
    float xr0 = xr[(size_t)node * 128 + t], xr1 = xr[(size_t)node * 128 + 64 + t];
    // self loop (src = dst = node, ea = loop_attr[node])
    float ee0 = 0.f, ee1 = 0.f;
    #pragma unroll
    for (int k = 0; k < 16; k++){
      float a = lattr[node * 16 + k];
      ee0 = fmaf(a, we0[k], ee0);
      ee1 = fmaf(a, we1[k], ee1);
    }
    float xs0 = xl[(size_t)node * 128 + t], xs1 = xl[(size_t)node * 128 + 64 + t];
    float m0 = xs0 + xr0 + ee0; m0 = m0 > 0.f ? m0 : NEG_SLOPE * m0;
    float m1 = xs1 + xr1 + ee1; m1 = m1 > 0.f ? m1 : NEG_SLOPE * m1;
    float l0 = gsum32(m0 * att0);
    float l1 = gsum32(m1 * att1);
    float mx0 = l0, den0 = 1.f, acc0 = xs0;
    float mx1 = l1, den1 = 1.f, acc1 = xs1;
    int beg = ptr[node], end = ptr[node + 1];
    for (int i = beg; i < end; i++){
      int e = eid[i];
      int s = srcs[e];
      const float* ea = eattr + (size_t)e * 16;
      ee0 = 0.f; ee1 = 0.f;
      #pragma unroll
      for (int k = 0; k < 16; k++){
        float a = ea[k];
        ee0 = fmaf(a, we0[k], ee0);
        ee1 = fmaf(a, we1[k], ee1);
      }
      xs0 = xl[(size_t)s * 128 + t]; xs1 = xl[(size_t)s * 128 + 64 + t];
      m0 = xs0 + xr0 + ee0; m0 = m0 > 0.f ? m0 : NEG_SLOPE * m0;
      m1 = xs1 + xr1 + ee1; m1 = m1 > 0.f ? m1 : NEG_SLOPE * m1;
      l0 = gsum32(m0 * att0);
      l1 = gsum32(m1 * att1);
      float nm0 = fmaxf(mx0, l0);
      float sc0 = __expf(mx0 - nm0), p0 = __expf(l0 - nm0);
      den0 = den0 * sc0 + p0; acc0 = acc0 * sc0 + p0 * xs0; mx0 = nm0;
      float nm1 = fmaxf(mx1, l1);
      float sc1 = __expf(mx1 - nm1), p1 = __expf(l1 - nm1);
      den1 = den1 * sc1 + p1; acc1 = acc1 * sc1 + p1 * xs1; mx1 = nm1;
    }
    float o0 = acc0 / den0 + cb0; o0 = o0 > 0.f ? o0 : expm1f(o0);
    float o1 = acc1 / den1 + cb1; o1 = o1 > 0.f ? o1 : expm1f(o1);
    hout[(size_t)node * 128 + t] = o0;
    hout[(size_t)node * 128 + 64 + t] = o1;
  }
}

// ---------------- LayerNorm + ReLU-MLP head, one wave per node ----------------
__launch_bounds__(64)
__global__ void k_head(const float* __restrict__ h, const float* __restrict__ g,
                       const float* __restrict__ b, const float* __restrict__ w1,
                       const float* __restrict__ b1, const float* __restrict__ w2,
                       const float* __restrict__ b2, float* __restrict__ out, int N){
  __shared__ float sn[128];
  int node = blockIdx.x;
  int t = threadIdx.x;
  float h0 = h[(size_t)node * 128 + t], h1 = h[(size_t)node * 128 + 64 + t];
  float mu = wsum64(h0 + h1) * (1.f / 128.f);
  float d0 = h0 - mu, d1 = h1 - mu;
  float var = wsum64(d0 * d0 + d1 * d1) * (1.f / 128.f);
  float rstd = rsqrtf(var + LN_EPS);
  sn[t]      = d0 * rstd * g[t]      + b[t];
  sn[t + 64] = d1 * rstd * g[t + 64] + b[t + 64];
  __syncthreads();
  float a = b1[t];
  for (int k = 0; k < 128; k++) a = fmaf(sn[k], w1[k * 64 + t], a);
  a = fmaxf(a, 0.f);
  float p0 = a * w2[t * 3 + 0], p1 = a * w2[t * 3 + 1], p2 = a * w2[t * 3 + 2];
  p0 = wsum64(p0); p1 = wsum64(p1); p2 = wsum64(p2);
  if (t == 0){
    out[(size_t)node * 3 + 0] = p0 + b2[0];
    out[(size_t)node * 3 + 1] = p1 + b2[1];
    out[(size_t)node * 3 + 2] = p2 + b2[2];
  }
}

extern "C" void kernel_launch(void* const* d_in, const int* in_sizes, int n_in,
                              void* d_out, int out_size, void* d_ws, size_t ws_size,
                              hipStream_t stream){
  const float* x    = (const float*)d_in[0];
  const int*   ei   = (const int*)d_in[1];   // int32 (JAX x64 disabled)
  const float* ea   = (const float*)d_in[2];
  const float* in_w = (const float*)d_in[3];
  const float* in_b = (const float*)d_in[4];
  const float* Wl   = (const float*)d_in[5];
  const float* bl   = (const float*)d_in[6];
  const float* Wr   = (const float*)d_in[7];
  const float* br   = (const float*)d_in[8];
  const float* We   = (const float*)d_in[9];
  const float* att  = (const float*)d_in[10];
  const float* cb   = (const float*)d_in[11];
  const float* lng  = (const float*)d_in[12];
  const float* lnb  = (const float*)d_in[13];
  const float* h1w  = (const float*)d_in[14];
  const float* h1b  = (const float*)d_in[15];
  const float* h2w  = (const float*)d_in[16];
  const float* h2b  = (const float*)d_in[17];
  float* out = (float*)d_out;

  int N = in_sizes[0] / 128;
  int E = in_sizes[1] / 2;
  const int* src = ei;
  const int* dst = ei + E;

  char* w = (char*)d_ws;
  size_t off = 0;
  auto alloc = [&](size_t bytes) -> char* {
    char* p = w + off;
    off = (off + bytes + 255) & ~(size_t)255;
    return p;
  };
  int*   deg   = (int*)alloc((size_t)N * 4);
  int*   cnt   = (int*)alloc((size_t)N * 4);
  int*   ptr   = (int*)alloc((size_t)(N + 1) * 4);
  int*   eid   = (int*)alloc((size_t)E * 4);
  float* lattr = (float*)alloc((size_t)N * 16 * 4);
  float* h     = (float*)alloc((size_t)N * 128 * 4);
  float* xlb   = (float*)alloc((size_t)N * 128 * 4);
  float* xrb   = (float*)alloc((size_t)N * 128 * 4);

  hipMemsetAsync(deg, 0, (size_t)N * 4, stream);
  hipMemsetAsync(cnt, 0, (size_t)N * 4, stream);
  k_count<<<(E + 255) / 256, 256, 0, stream>>>(dst, deg, E);
  k_scan<<<1, 1024, 0, stream>>>(deg, ptr, N);
  k_fill<<<(E + 255) / 256, 256, 0, stream>>>(dst, cnt, ptr, eid, E);
  k_loop_attr<<<(N * 16 + 255) / 256, 256, 0, stream>>>(ea, ptr, eid, lattr, N);

  k_gemm128<<<(N + 63) / 64, 256, 0, stream>>>(x, in_w, in_b, h, N);
  for (int l = 0; l < 2; l++){
    k_gemm128<<<(N + 63) / 64, 256, 0, stream>>>(h, Wl + l * 16384, bl + l * 128, xlb, N);
    k_gemm128<<<(N + 63) / 64, 256, 0, stream>>>(h, Wr + l * 16384, br + l * 128, xrb, N);
    k_gat<<<(N + 3) / 4, 64, 0, stream>>>(xlb, xrb, ea, lattr, src, ptr, eid,
                                          We + l * 2048, att + l * 128, cb + l * 128, h, N);
  }
  k_head<<<N, 64, 0, stream>>>(h, lng, lnb, h1w, h1b, h2w, h2b, out, N);
}

// Round 2
// 666.952 us; speedup vs baseline: 1.1335x; 1.1335x over previous
//
#include <hip/hip_runtime.h>

#define NEG_SLOPE 0.2f
#define LN_EPS 1e-5f

__device__ __forceinline__ float wsum64(float v){
  #pragma unroll
  for (int o = 32; o >= 1; o >>= 1) v += __shfl_xor(v, o);
  return v;
}
__device__ __forceinline__ float gsum32(float v){
  #pragma unroll
  for (int o = 16; o >= 1; o >>= 1) v += __shfl_xor(v, o);
  return v;
}
__device__ __forceinline__ float dot16(const float4 a0, const float4 a1,
                                       const float4 a2, const float4 a3,
                                       const float* w){
  float s = a0.x * w[0];
  s = fmaf(a0.y, w[1], s);  s = fmaf(a0.z, w[2], s);  s = fmaf(a0.w, w[3], s);
  s = fmaf(a1.x, w[4], s);  s = fmaf(a1.y, w[5], s);  s = fmaf(a1.z, w[6], s);
  s = fmaf(a1.w, w[7], s);  s = fmaf(a2.x, w[8], s);  s = fmaf(a2.y, w[9], s);
  s = fmaf(a2.z, w[10], s); s = fmaf(a2.w, w[11], s); s = fmaf(a3.x, w[12], s);
  s = fmaf(a3.y, w[13], s); s = fmaf(a3.z, w[14], s); s = fmaf(a3.w, w[15], s);
  return s;
}

// ---------------- CSR build ----------------
__global__ void k_count(const int* __restrict__ dst, int* __restrict__ deg, int E){
  int e = blockIdx.x * blockDim.x + threadIdx.x;
  if (e < E) atomicAdd(&deg[dst[e]], 1);
}

// hierarchical scan: block-local exclusive scan + block sums
__global__ void k_scan_blk(const int* __restrict__ deg, int* __restrict__ part,
                           int* __restrict__ sums, int n){
  __shared__ int buf[256];
  int t = threadIdx.x, i = blockIdx.x * 256 + t;
  int v = (i < n) ? deg[i] : 0;
  buf[t] = v; __syncthreads();
  #pragma unroll
  for (int off = 1; off < 256; off <<= 1){
    int x = (t >= off) ? buf[t - off] : 0;
    __syncthreads(); buf[t] += x; __syncthreads();
  }
  if (i < n) part[i] = buf[t] - v;          // exclusive within block
  if (t == 255) sums[blockIdx.x] = buf[255];
}

__global__ void k_scan_top(int* __restrict__ sums, int nb){
  __shared__ int buf[256];
  int t = threadIdx.x;
  int v = (t < nb) ? sums[t] : 0;
  buf[t] = v; __syncthreads();
  #pragma unroll
  for (int off = 1; off < 256; off <<= 1){
    int x = (t >= off) ? buf[t - off] : 0;
    __syncthreads(); buf[t] += x; __syncthreads();
  }
  if (t < nb) sums[t] = buf[t] - v;         // exclusive block offsets
}

__global__ void k_scan_add(int* __restrict__ ptr, const int* __restrict__ sums,
                           int n, int Etot){
  int i = blockIdx.x * 256 + threadIdx.x;
  if (i < n) ptr[i] += sums[blockIdx.x];
  if (i == 0) ptr[n] = Etot;
}

__global__ void k_fill(const int* __restrict__ dst, int* __restrict__ cnt,
                       const int* __restrict__ ptr, int* __restrict__ eid, int E){
  int e = blockIdx.x * blockDim.x + threadIdx.x;
  if (e < E){
    int d = dst[e];
    int pos = atomicAdd(&cnt[d], 1);
    eid[ptr[d] + pos] = e;
  }
}

// loop_attr[n] = mean of incoming edge_attr; 16 lanes per node
__global__ void k_loop_attr(const float* __restrict__ eattr, const int* __restrict__ ptr,
                            const int* __restrict__ eid, float* __restrict__ lattr, int N){
  int idx = blockIdx.x * blockDim.x + threadIdx.x;
  int node = idx >> 4, dim = idx & 15;
  if (node >= N) return;
  int beg = ptr[node], end = ptr[node + 1];
  float s = 0.f;
  for (int i = beg; i < end; i++){
    int e = eid[i];
    s += eattr[(size_t)e * 16 + dim];
  }
  float dg = (float)(end - beg);
  lattr[idx] = s / fmaxf(dg, 1.0f);
}

// ---------------- Y[M,128] = X[M,128] @ W[128,128] + b ----------------
__launch_bounds__(256)
__global__ void k_gemm128(const float* __restrict__ X, const float* __restrict__ W,
                          const float* __restrict__ bias, float* __restrict__ Y, int M){
  __shared__ float Xs[64][129];
  int t = threadIdx.x;
  int rowBase = blockIdx.x * 64;
  int lr = t >> 5, lc = (t & 31) * 4;
  #pragma unroll
  for (int p = 0; p < 8; p++){
    int r = p * 8 + lr, gr = rowBase + r;
    float4 v = make_float4(0.f, 0.f, 0.f, 0.f);
    if (gr < M) v = *(const float4*)(X + (size_t)gr * 128 + lc);
    Xs[r][lc] = v.x; Xs[r][lc + 1] = v.y; Xs[r][lc + 2] = v.z; Xs[r][lc + 3] = v.w;
  }
  __syncthreads();
  int c0 = (t & 31) * 4, r0 = (t >> 5) * 8;
  float4 bv = *(const float4*)(bias + c0);
  float acc[8][4];
  #pragma unroll
  for (int i = 0; i < 8; i++){ acc[i][0] = bv.x; acc[i][1] = bv.y; acc[i][2] = bv.z; acc[i][3] = bv.w; }
  for (int k = 0; k < 128; k++){
    float4 wv = *(const float4*)(W + k * 128 + c0);
    #pragma unroll
    for (int i = 0; i < 8; i++){
      float x = Xs[r0 + i][k];
      acc[i][0] = fmaf(x, wv.x, acc[i][0]);
      acc[i][1] = fmaf(x, wv.y, acc[i][1]);
      acc[i][2] = fmaf(x, wv.z, acc[i][2]);
      acc[i][3] = fmaf(x, wv.w, acc[i][3]);
    }
  }
  #pragma unroll
  for (int i = 0; i < 8; i++){
    int gr = rowBase + r0 + i;
    if (gr < M){
      float4 o; o.x = acc[i][0]; o.y = acc[i][1]; o.z = acc[i][2]; o.w = acc[i][3];
      *(float4*)(Y + (size_t)gr * 128 + c0) = o;
    }
  }
}

// fused pair: YL = X@WL + bL ; YR = X@WR + bR  (shares the X staging)
__launch_bounds__(256)
__global__ void k_gemm_lr(const float* __restrict__ X,
                          const float* __restrict__ WL, const float* __restrict__ bL,
                          const float* __restrict__ WR, const float* __restrict__ bR,
                          float* __restrict__ YL, float* __restrict__ YR, int M){
  __shared__ float Xs[64][129];
  int t = threadIdx.x;
  int rowBase = blockIdx.x * 64;
  int lr = t >> 5, lc = (t & 31) * 4;
  #pragma unroll
  for (int p = 0; p < 8; p++){
    int r = p * 8 + lr, gr = rowBase + r;
    float4 v = make_float4(0.f, 0.f, 0.f, 0.f);
    if (gr < M) v = *(const float4*)(X + (size_t)gr * 128 + lc);
    Xs[r][lc] = v.x; Xs[r][lc + 1] = v.y; Xs[r][lc + 2] = v.z; Xs[r][lc + 3] = v.w;
  }
  __syncthreads();
  int c0 = (t & 31) * 4, r0 = (t >> 5) * 8;
  float4 bv = *(const float4*)(bL + c0);
  float4 cv = *(const float4*)(bR + c0);
  float aL[8][4], aR[8][4];
  #pragma unroll
  for (int i = 0; i < 8; i++){
    aL[i][0] = bv.x; aL[i][1] = bv.y; aL[i][2] = bv.z; aL[i][3] = bv.w;
    aR[i][0] = cv.x; aR[i][1] = cv.y; aR[i][2] = cv.z; aR[i][3] = cv.w;
  }
  for (int k = 0; k < 128; k++){
    float4 wl = *(const float4*)(WL + k * 128 + c0);
    float4 wr = *(const float4*)(WR + k * 128 + c0);
    #pragma unroll
    for (int i = 0; i < 8; i++){
      float x = Xs[r0 + i][k];
      aL[i][0] = fmaf(x, wl.x, aL[i][0]); aL[i][1] = fmaf(x, wl.y, aL[i][1]);
      aL[i][2] = fmaf(x, wl.z, aL[i][2]); aL[i][3] = fmaf(x, wl.w, aL[i][3]);
      aR[i][0] = fmaf(x, wr.x, aR[i][0]); aR[i][1] = fmaf(x, wr.y, aR[i][1]);
      aR[i][2] = fmaf(x, wr.z, aR[i][2]); aR[i][3] = fmaf(x, wr.w, aR[i][3]);
    }
  }
  #pragma unroll
  for (int i = 0; i < 8; i++){
    int gr = rowBase + r0 + i;
    if (gr < M){
      float4 o; o.x = aL[i][0]; o.y = aL[i][1]; o.z = aL[i][2]; o.w = aL[i][3];
      *(float4*)(YL + (size_t)gr * 128 + c0) = o;
      float4 q; q.x = aR[i][0]; q.y = aR[i][1]; q.z = aR[i][2]; q.w = aR[i][3];
      *(float4*)(YR + (size_t)gr * 128 + c0) = q;
    }
  }
}

// ---------------- GAT layer: wave/4-nodes, online softmax, prefetched CSR ----------------
__launch_bounds__(256)
__global__ void k_gat(const float* __restrict__ xl, const float* __restrict__ xr,
                      const float* __restrict__ eattr, const float* __restrict__ lattr,
                      const int* __restrict__ srcs, const int* __restrict__ ptr,
                      const int* __restrict__ eid,
                      const float* __restrict__ We, const float* __restrict__ att,
                      const float* __restrict__ cb, float* __restrict__ hout, int N){
  const int t = threadIdx.x & 63;
  const int wv = threadIdx.x >> 6;
  const int node0 = (blockIdx.x * 4 + wv) * 4;
  if (node0 >= N) return;

  float we0[16], we1[16];
  #pragma unroll
  for (int k = 0; k < 16; k++){ we0[k] = We[k * 128 + t]; we1[k] = We[k * 128 + 64 + t]; }
  const float att0 = att[t], att1 = att[64 + t];
  const float cb0 = cb[t],  cb1 = cb[64 + t];

  // wave-uniform CSR ranges for the 4 nodes, then lane-parallel (e,src) preload
  int pv[5];
  #pragma unroll
  for (int j = 0; j < 5; j++){
    int nn = node0 + j; nn = nn > N ? N : nn;
    pv[j] = __builtin_amdgcn_readfirstlane(ptr[nn]);
  }
  int elv[4], slv[4];
  #pragma unroll
  for (int j = 0; j < 4; j++){ int idx = pv[j] + t; elv[j] = (idx < pv[j + 1]) ? eid[idx] : 0; }
  #pragma unroll
  for (int j = 0; j < 4; j++){ slv[j] = (pv[j] + t < pv[j + 1]) ? srcs[elv[j]] : 0; }

  for (int j = 0; j < 4; j++){
    const int node = node0 + j;
    if (node >= N) break;
    const int beg = pv[j], end = pv[j + 1];

    // self loop (src = dst = node, ea = loop_attr[node])
    const float4* lap = (const float4*)(lattr + (size_t)node * 16);
    float4 la0 = lap[0], la1 = lap[1], la2 = lap[2], la3 = lap[3];
    float xr0 = xr[(size_t)node * 128 + t], xr1 = xr[(size_t)node * 128 + 64 + t];
    float xs0 = xl[(size_t)node * 128 + t], xs1 = xl[(size_t)node * 128 + 64 + t];
    float m0 = xs0 + xr0 + dot16(la0, la1, la2, la3, we0);
    float m1 = xs1 + xr1 + dot16(la0, la1, la2, la3, we1);
    m0 = m0 > 0.f ? m0 : NEG_SLOPE * m0;
    m1 = m1 > 0.f ? m1 : NEG_SLOPE * m1;
    float mx0 = gsum32(m0 * att0), mx1 = gsum32(m1 * att1);
    float den0 = 1.f, acc0 = xs0, den1 = 1.f, acc1 = xs1;

    int el = elv[j], sl = slv[j];
    for (int base = beg; base < end; base += 64){
      int rem = end - base;
      const int cn = __builtin_amdgcn_readfirstlane(rem < 64 ? rem : 64);
      if (base != beg){
        int idx = base + t;
        el = (idx < end) ? eid[idx] : 0;
        sl = (idx < end) ? srcs[el] : 0;
      }
      // distance-1 prefetch of xl + edge_attr (edge ids known in-register)
      int sN = __builtin_amdgcn_readfirstlane(__shfl(sl, 0));
      int eN = __builtin_amdgcn_readfirstlane(__shfl(el, 0));
      const float* xp = xl + (size_t)sN * 128;
      float xaN = xp[t], xbN = xp[64 + t];
      const float4* ep = (const float4*)(eattr + (size_t)eN * 16);
      float4 eaN0 = ep[0], eaN1 = ep[1], eaN2 = ep[2], eaN3 = ep[3];
      for (int ii = 0; ii < cn; ii++){
        const float xa = xaN, xb = xbN;
        const float4 ea0 = eaN0, ea1 = eaN1, ea2 = eaN2, ea3 = eaN3;
        if (ii + 1 < cn){
          sN = __builtin_amdgcn_readfirstlane(__shfl(sl, ii + 1));
          eN = __builtin_amdgcn_readfirstlane(__shfl(el, ii + 1));
          const float* xp2 = xl + (size_t)sN * 128;
          xaN = xp2[t]; xbN = xp2[64 + t];
          const float4* ep2 = (const float4*)(eattr + (size_t)eN * 16);
          eaN0 = ep2[0]; eaN1 = ep2[1]; eaN2 = ep2[2]; eaN3 = ep2[3];
        }
        float n0 = xa + xr0 + dot16(ea0, ea1, ea2, ea3, we0);
        float n1 = xb + xr1 + dot16(ea0, ea1, ea2, ea3, we1);
        n0 = n0 > 0.f ? n0 : NEG_SLOPE * n0;
        n1 = n1 > 0.f ? n1 : NEG_SLOPE * n1;
        float l0 = gsum32(n0 * att0);
        float l1 = gsum32(n1 * att1);
        float nm0 = fmaxf(mx0, l0), nm1 = fmaxf(mx1, l1);
        float sc0 = __expf(mx0 - nm0), p0 = __expf(l0 - nm0);
        float sc1 = __expf(mx1 - nm1), p1 = __expf(l1 - nm1);
        den0 = den0 * sc0 + p0; acc0 = acc0 * sc0 + p0 * xa; mx0 = nm0;
        den1 = den1 * sc1 + p1; acc1 = acc1 * sc1 + p1 * xb; mx1 = nm1;
      }
    }
    float o0 = acc0 / den0 + cb0; o0 = o0 > 0.f ? o0 : expm1f(o0);
    float o1 = acc1 / den1 + cb1; o1 = o1 > 0.f ? o1 : expm1f(o1);
    hout[(size_t)node * 128 + t] = o0;
    hout[(size_t)node * 128 + 64 + t] = o1;
  }
}

// ---------------- LayerNorm + ReLU-MLP head, wave per node, 4 waves/block ----------------
__launch_bounds__(256)
__global__ void k_head(const float* __restrict__ h, const float* __restrict__ g,
                       const float* __restrict__ b, const float* __restrict__ w1,
                       const float* __restrict__ b1, const float* __restrict__ w2,
                       const float* __restrict__ b2, float* __restrict__ out, int N){
  __shared__ float sn[4][128];
  const int t = threadIdx.x & 63, wv = threadIdx.x >> 6;
  const int node = blockIdx.x * 4 + wv;
  float h0 = 0.f, h1 = 0.f;
  if (node < N){ h0 = h[(size_t)node * 128 + t]; h1 = h[(size_t)node * 128 + 64 + t]; }
  float mu = wsum64(h0 + h1) * (1.f / 128.f);
  float d0 = h0 - mu, d1 = h1 - mu;
  float var = wsum64(d0 * d0 + d1 * d1) * (1.f / 128.f);
  float rstd = rsqrtf(var + LN_EPS);
  sn[wv][t]      = d0 * rstd * g[t]      + b[t];
  sn[wv][t + 64] = d1 * rstd * g[t + 64] + b[t + 64];
  __syncthreads();
  float a = b1[t];
  #pragma unroll
  for (int k4 = 0; k4 < 32; k4++){
    float4 v = *(const float4*)&sn[wv][k4 * 4];
    a = fmaf(v.x, w1[(k4 * 4 + 0) * 64 + t], a);
    a = fmaf(v.y, w1[(k4 * 4 + 1) * 64 + t], a);
    a = fmaf(v.z, w1[(k4 * 4 + 2) * 64 + t], a);
    a = fmaf(v.w, w1[(k4 * 4 + 3) * 64 + t], a);
  }
  a = fmaxf(a, 0.f);
  float p0 = a * w2[t * 3 + 0], p1 = a * w2[t * 3 + 1], p2 = a * w2[t * 3 + 2];
  p0 = wsum64(p0); p1 = wsum64(p1); p2 = wsum64(p2);
  if (node < N && t == 0){
    out[(size_t)node * 3 + 0] = p0 + b2[0];
    out[(size_t)node * 3 + 1] = p1 + b2[1];
    out[(size_t)node * 3 + 2] = p2 + b2[2];
  }
}

extern "C" void kernel_launch(void* const* d_in, const int* in_sizes, int n_in,
                              void* d_out, int out_size, void* d_ws, size_t ws_size,
                              hipStream_t stream){
  const float* x    = (const float*)d_in[0];
  const int*   ei   = (const int*)d_in[1];
  const float* ea   = (const float*)d_in[2];
  const float* in_w = (const float*)d_in[3];
  const float* in_b = (const float*)d_in[4];
  const float* Wl   = (const float*)d_in[5];
  const float* bl   = (const float*)d_in[6];
  const float* Wr   = (const float*)d_in[7];
  const float* br   = (const float*)d_in[8];
  const float* We   = (const float*)d_in[9];
  const float* att  = (const float*)d_in[10];
  const float* cb   = (const float*)d_in[11];
  const float* lng  = (const float*)d_in[12];
  const float* lnb  = (const float*)d_in[13];
  const float* h1w  = (const float*)d_in[14];
  const float* h1b  = (const float*)d_in[15];
  const float* h2w  = (const float*)d_in[16];
  const float* h2b  = (const float*)d_in[17];
  float* out = (float*)d_out;

  int N = in_sizes[0] / 128;
  int E = in_sizes[1] / 2;
  const int* src = ei;
  const int* dst = ei + E;

  char* w = (char*)d_ws;
  size_t off = 0;
  auto alloc = [&](size_t bytes) -> char* {
    char* p = w + off;
    off = (off + bytes + 255) & ~(size_t)255;
    return p;
  };
  int*   deg   = (int*)alloc((size_t)N * 4);
  int*   cnt   = (int*)alloc((size_t)N * 4);
  int*   ptr   = (int*)alloc((size_t)(N + 1) * 4);
  int*   eid   = (int*)alloc((size_t)E * 4);
  int*   bsum  = (int*)alloc(256 * 4);
  float* lattr = (float*)alloc((size_t)N * 16 * 4);
  float* h     = (float*)alloc((size_t)N * 128 * 4);
  float* xlb   = (float*)alloc((size_t)N * 128 * 4);
  float* xrb   = (float*)alloc((size_t)N * 128 * 4);

  int nb = (N + 255) / 256;  // 196 <= 256
  hipMemsetAsync(deg, 0, (size_t)N * 4, stream);
  hipMemsetAsync(cnt, 0, (size_t)N * 4, stream);
  k_count<<<(E + 255) / 256, 256, 0, stream>>>(dst, deg, E);
  k_scan_blk<<<nb, 256, 0, stream>>>(deg, ptr, bsum, N);
  k_scan_top<<<1, 256, 0, stream>>>(bsum, nb);
  k_scan_add<<<nb, 256, 0, stream>>>(ptr, bsum, N, E);
  k_fill<<<(E + 255) / 256, 256, 0, stream>>>(dst, cnt, ptr, eid, E);
  k_loop_attr<<<(N * 16 + 255) / 256, 256, 0, stream>>>(ea, ptr, eid, lattr, N);

  k_gemm128<<<(N + 63) / 64, 256, 0, stream>>>(x, in_w, in_b, h, N);
  for (int l = 0; l < 2; l++){
    k_gemm_lr<<<(N + 63) / 64, 256, 0, stream>>>(h, Wl + l * 16384, bl + l * 128,
                                                 Wr + l * 16384, br + l * 128, xlb, xrb, N);
    k_gat<<<(N + 15) / 16, 256, 0, stream>>>(xlb, xrb, ea, lattr, src, ptr, eid,
                                             We + l * 2048, att + l * 128, cb + l * 128, h, N);
  }
  k_head<<<(N + 3) / 4, 256, 0, stream>>>(h, lng, lnb, h1w, h1b, h2w, h2b, out, N);
}